// Round 12
// baseline (136.229 us; speedup 1.0000x reference)
//
#include <hip/hip_runtime.h>

// Truncated signature, depth=3, C=8, B=512, L=8192.
// Kernel 1 (hybrid-broadcast): one wave per (sample,chunk), sequential Chen steps.
//   lane (a,b)=(lane>>3,lane&7) owns S2[a][b], S3[a][b][0..7].
//   S3[k] += cf * dx2[k][u];  cf = S2 + S1*db/2 + da*db/6  (dx2 = dx/2, x2 at end).
//   Broadcast operand dx2[k][u] split across pipes:
//     k=0..3: uniform ds_read_b128 from lo-only A array [t][4]   (DS pipe)
//     k=4..7: v_readlane from staging regs e0t/e1t, lanes 32..56+q (VALU/SALU)
//   Per-lane da/db from Bc [c][t] stride-68 array (4x b128 per 8 steps).
//   Per-wave private LDS, no barriers. G=32 chunks/sample.
// Kernel 2: per-sample in-order Chen combine of the G chunk signatures.

typedef float f2 __attribute__((ext_vector_type(2)));

constexpr int B_ = 512;
constexpr int C_ = 8;
constexpr int L_ = 8192;
constexpr int NINC = L_ - 1;      // 8191 increments
constexpr int SIGDIM = 584;       // 8 + 64 + 512
constexpr int TILE = 64;          // steps per LDS tile
constexpr int BSTR = 68;          // Bc row stride (floats)
constexpr int BWSZ = C_ * BSTR;   // 544
constexpr int AWSZ = 256;         // A lo-half: [64][4] floats

static __device__ __forceinline__ float rl(float v, int l) {
  return __int_as_float(__builtin_amdgcn_readlane(__float_as_int(v), l));
}

// One step. DAV/DBV halved increments; P4 = ch0-3 dx2 (from LDS);
// EC = staging-reg component for this step; Q = source quad (si) index.
#define HSTEP(DAV, DBV, P4, EC, Q)                                         \
  do {                                                                     \
    const f2 wz = __builtin_elementwise_fma(                               \
        f2{(DAV), (DAV)}, f2{(2.f/3.f), (4.f/3.f)}, f2{s1a, s1a});         \
    const float cf = __builtin_fmaf((DBV), wz.x, S2);                      \
    S2  = __builtin_fmaf((DBV), wz.y, cf);                                 \
    s1a = __builtin_fmaf((DAV), 2.f, s1a);                                 \
    const f2 cf2 = {cf, cf};                                               \
    S3p[0] = __builtin_elementwise_fma(cf2, f2{(P4).x, (P4).y}, S3p[0]);   \
    S3p[1] = __builtin_elementwise_fma(cf2, f2{(P4).z, (P4).w}, S3p[1]);   \
    S3h0 = __builtin_fmaf(cf, rl((EC), 32 + (Q)), S3h0);                   \
    S3h1 = __builtin_fmaf(cf, rl((EC), 40 + (Q)), S3h1);                   \
    S3h2 = __builtin_fmaf(cf, rl((EC), 48 + (Q)), S3h2);                   \
    S3h3 = __builtin_fmaf(cf, rl((EC), 56 + (Q)), S3h3);                   \
  } while (0)

__global__ __launch_bounds__(256, 6)
void sig_chunks_kernel(const float* __restrict__ path, float* __restrict__ csig,
                       int G, int CPC) {
  __shared__ __align__(16) float As[4][AWSZ];   // 4 KB
  __shared__ __align__(16) float Bs[4][BWSZ];   // 8.7 KB
  const int wid  = __builtin_amdgcn_readfirstlane((int)(threadIdx.x >> 6));
  const int lane = (int)(threadIdx.x & 63);
  const int ia = lane >> 3;   // 'a' == staging channel
  const int ib = lane & 7;    // 'b' == staging position
  const int wglob = __builtin_amdgcn_readfirstlane((int)blockIdx.x) * 4 + wid;
  const int samp = wglob / G;
  const int g    = wglob - samp * G;
  const int ts = g * CPC;
  const int te = (ts + CPC < NINC) ? (ts + CPC) : NINC;   // exclusive end
  const float* pbase = path + (size_t)samp * (C_ * L_);
  float* as_ = As[wid];
  float* bs  = Bs[wid];

  const int si = ib;
  const float* prow = pbase + ia * L_;
  const int grp = lane & ~7;
  const float* pa = bs + ia * BSTR;
  const float* pb = bs + ib * BSTR;

  f2 S3p[2];
  S3p[0] = f2{0.f, 0.f};
  S3p[1] = f2{0.f, 0.f};
  float S3h0 = 0.f, S3h1 = 0.f, S3h2 = 0.f, S3h3 = 0.f;
  float S2 = 0.f, s1a = 0.f;

  const int ntiles = (CPC + TILE - 1) / TILE;   // uniform across grid

  // prologue: prefetch tile 0 + boundary
  float4 r0 = *(const float4*)(prow + ts + si * 4);
  float4 r1 = *(const float4*)(prow + ts + 32 + si * 4);
  float bnd = prow[ts + TILE];
  float4 e0t, e1t;   // current tile's halved diffs (live through compute!)

  for (int tt = 0; tt < ntiles; ++tt) {
    const int t0 = ts + tt * TILE;
    const int cnt_ = te - t0;
    const int cnt = (cnt_ < TILE) ? cnt_ : TILE;

    // ---- stage tile tt: halved diffs -> regs + Bc; lo channels -> A ----
    {
      const float4 v0 = r0, v1 = r1;
      const float sA = __shfl(v0.x, lane + 1);
      const float sB = __shfl(v1.x, grp);
      const float sC = __shfl(v1.x, lane + 1);
      const float n0 = (si == 7) ? sB : sA;
      const float n1 = (si == 7) ? bnd : sC;
      e0t.x = (v0.y - v0.x) * 0.5f;
      e0t.y = (v0.z - v0.y) * 0.5f;
      e0t.z = (v0.w - v0.z) * 0.5f;
      e0t.w = (n0 - v0.w) * 0.5f;
      e1t.x = (v1.y - v1.x) * 0.5f;
      e1t.y = (v1.z - v1.y) * 0.5f;
      e1t.z = (v1.w - v1.z) * 0.5f;
      e1t.w = (n1 - v1.w) * 0.5f;
      *(float4*)(bs + ia * BSTR + si * 4) = e0t;
      *(float4*)(bs + ia * BSTR + 32 + si * 4) = e1t;
      if (ia < 4) {   // lo-channel transpose into A [t][4]
        float* aw = as_ + ia;
        const int tl = si * 4;
        aw[(tl + 0) * 4] = e0t.x;
        aw[(tl + 1) * 4] = e0t.y;
        aw[(tl + 2) * 4] = e0t.z;
        aw[(tl + 3) * 4] = e0t.w;
        aw[(32 + tl + 0) * 4] = e1t.x;
        aw[(32 + tl + 1) * 4] = e1t.y;
        aw[(32 + tl + 2) * 4] = e1t.z;
        aw[(32 + tl + 3) * 4] = e1t.w;
      }
    }

    // ---- prefetch tile tt+1 (r0/r1 free; e0t/e1t stay live) ----
    if (tt + 1 < ntiles) {
      const int t1g = t0 + TILE;
      r0 = *(const float4*)(prow + t1g + si * 4);
      r1 = *(const float4*)(prow + t1g + 32 + si * 4);
      const int bn = t1g + TILE;
      bnd = (bn < L_) ? prow[bn] : 0.f;
    }

    // ---- compute tile tt ----
    if (cnt == TILE) {
      // first half: steps 0..31, hi-broadcast from e0t
#pragma unroll
      for (int blk = 0; blk < 4; ++blk) {
        const int u0 = blk * 8;
        const float4 a0 = *(const float4*)(pa + u0);
        const float4 a1 = *(const float4*)(pa + u0 + 4);
        const float4 b0 = *(const float4*)(pb + u0);
        const float4 b1 = *(const float4*)(pb + u0 + 4);
        float4 P;
        P = *(const float4*)(as_ + (u0 + 0) * 4); HSTEP(a0.x, b0.x, P, e0t.x, blk * 2);
        P = *(const float4*)(as_ + (u0 + 1) * 4); HSTEP(a0.y, b0.y, P, e0t.y, blk * 2);
        P = *(const float4*)(as_ + (u0 + 2) * 4); HSTEP(a0.z, b0.z, P, e0t.z, blk * 2);
        P = *(const float4*)(as_ + (u0 + 3) * 4); HSTEP(a0.w, b0.w, P, e0t.w, blk * 2);
        P = *(const float4*)(as_ + (u0 + 4) * 4); HSTEP(a1.x, b1.x, P, e0t.x, blk * 2 + 1);
        P = *(const float4*)(as_ + (u0 + 5) * 4); HSTEP(a1.y, b1.y, P, e0t.y, blk * 2 + 1);
        P = *(const float4*)(as_ + (u0 + 6) * 4); HSTEP(a1.z, b1.z, P, e0t.z, blk * 2 + 1);
        P = *(const float4*)(as_ + (u0 + 7) * 4); HSTEP(a1.w, b1.w, P, e0t.w, blk * 2 + 1);
      }
      // second half: steps 32..63, hi-broadcast from e1t
#pragma unroll
      for (int blk = 0; blk < 4; ++blk) {
        const int u0 = 32 + blk * 8;
        const float4 a0 = *(const float4*)(pa + u0);
        const float4 a1 = *(const float4*)(pa + u0 + 4);
        const float4 b0 = *(const float4*)(pb + u0);
        const float4 b1 = *(const float4*)(pb + u0 + 4);
        float4 P;
        P = *(const float4*)(as_ + (u0 + 0) * 4); HSTEP(a0.x, b0.x, P, e1t.x, blk * 2);
        P = *(const float4*)(as_ + (u0 + 1) * 4); HSTEP(a0.y, b0.y, P, e1t.y, blk * 2);
        P = *(const float4*)(as_ + (u0 + 2) * 4); HSTEP(a0.z, b0.z, P, e1t.z, blk * 2);
        P = *(const float4*)(as_ + (u0 + 3) * 4); HSTEP(a0.w, b0.w, P, e1t.w, blk * 2);
        P = *(const float4*)(as_ + (u0 + 4) * 4); HSTEP(a1.x, b1.x, P, e1t.x, blk * 2 + 1);
        P = *(const float4*)(as_ + (u0 + 5) * 4); HSTEP(a1.y, b1.y, P, e1t.y, blk * 2 + 1);
        P = *(const float4*)(as_ + (u0 + 6) * 4); HSTEP(a1.z, b1.z, P, e1t.z, blk * 2 + 1);
        P = *(const float4*)(as_ + (u0 + 7) * 4); HSTEP(a1.w, b1.w, P, e1t.w, blk * 2 + 1);
      }
    } else {
      // tail tile (last chunk's last tile, cnt=63): cold path, uniform b32 reads.
      for (int u = 0; u < cnt; ++u) {
        const float dav = pa[u];
        const float dbv = pb[u];
        const f2 wz = __builtin_elementwise_fma(
            f2{dav, dav}, f2{(2.f/3.f), (4.f/3.f)}, f2{s1a, s1a});
        const float cf = __builtin_fmaf(dbv, wz.x, S2);
        S2  = __builtin_fmaf(dbv, wz.y, cf);
        s1a = __builtin_fmaf(dav, 2.f, s1a);
        S3p[0].x = __builtin_fmaf(cf, bs[0 * BSTR + u], S3p[0].x);
        S3p[0].y = __builtin_fmaf(cf, bs[1 * BSTR + u], S3p[0].y);
        S3p[1].x = __builtin_fmaf(cf, bs[2 * BSTR + u], S3p[1].x);
        S3p[1].y = __builtin_fmaf(cf, bs[3 * BSTR + u], S3p[1].y);
        S3h0 = __builtin_fmaf(cf, bs[4 * BSTR + u], S3h0);
        S3h1 = __builtin_fmaf(cf, bs[5 * BSTR + u], S3h1);
        S3h2 = __builtin_fmaf(cf, bs[6 * BSTR + u], S3h2);
        S3h3 = __builtin_fmaf(cf, bs[7 * BSTR + u], S3h3);
      }
    }
  }

  float* cs = csig + ((size_t)samp * G + g) * SIGDIM;
  if (ib == 0) cs[ia] = s1a;
  cs[8 + lane] = S2;
  float4 o0, o1;
  o0.x = 2.f * S3p[0].x; o0.y = 2.f * S3p[0].y;
  o0.z = 2.f * S3p[1].x; o0.w = 2.f * S3p[1].y;
  o1.x = 2.f * S3h0; o1.y = 2.f * S3h1; o1.z = 2.f * S3h2; o1.w = 2.f * S3h3;
  *(float4*)(cs + 72 + lane * 8)     = o0;
  *(float4*)(cs + 72 + lane * 8 + 4) = o1;
}

__global__ __launch_bounds__(256)
void sig_combine_kernel(const float* __restrict__ csig, float* __restrict__ out, int G) {
  const int wid  = __builtin_amdgcn_readfirstlane((int)(threadIdx.x >> 6));
  const int lane = (int)(threadIdx.x & 63);
  const int ia = lane >> 3, ib = lane & 7;
  const int samp = __builtin_amdgcn_readfirstlane((int)blockIdx.x) * 4 + wid;
  const float* base = csig + (size_t)samp * G * SIGDIM;

  float R1a = base[ia];
  float R2  = base[8 + lane];
  float R3[8];
#pragma unroll
  for (int k = 0; k < 8; ++k) R3[k] = base[72 + lane * 8 + k];

  for (int g = 1; g < G; ++g) {
    const float* T = base + g * SIGDIM;
    float sT1[8];
#pragma unroll
    for (int k = 0; k < 8; ++k) sT1[k] = T[k];
    const float T1a  = T[ia];
    const float T1b  = T[ib];
    const float T2ab = T[8 + lane];
    float T2b[8], T3v[8];
#pragma unroll
    for (int k = 0; k < 8; ++k) T2b[k] = T[8 + ib * 8 + k];
#pragma unroll
    for (int k = 0; k < 8; ++k) T3v[k] = T[72 + lane * 8 + k];
    const float R1o = R1a, R2o = R2;
#pragma unroll
    for (int k = 0; k < 8; ++k)
      R3[k] += T3v[k] + R1o * T2b[k] + R2o * sT1[k];
    R2  += T2ab + R1o * T1b;
    R1a += T1a;
  }

  float* o = out + (size_t)samp * SIGDIM;
  if (ib == 0) o[ia] = R1a;
  o[8 + lane] = R2;
#pragma unroll
  for (int k = 0; k < 8; ++k) o[72 + lane * 8 + k] = R3[k];
}

extern "C" void kernel_launch(void* const* d_in, const int* in_sizes, int n_in,
                              void* d_out, int out_size, void* d_ws, size_t ws_size,
                              hipStream_t stream) {
  (void)in_sizes; (void)n_in; (void)out_size;
  const float* path = (const float*)d_in[0];
  float* out = (float*)d_out;
  float* ws  = (float*)d_ws;

  int G = 32;
  while (G > 1 && (size_t)B_ * G * SIGDIM * sizeof(float) > ws_size) G >>= 1;
  const int CPC = (NINC + G - 1) / G;   // increments per chunk

  sig_chunks_kernel<<<dim3(B_ * G / 4), dim3(256), 0, stream>>>(path, ws, G, CPC);
  sig_combine_kernel<<<dim3(B_ / 4), dim3(256), 0, stream>>>(ws, out, G);
}

// Round 15
// 115.983 us; speedup vs baseline: 1.1746x; 1.1746x over previous
//
#include <hip/hip_runtime.h>

// Truncated signature, depth=3, C=8, B=512, L=8192.
// Kernel 1 (R11 structure + register-double-buffered LDS pipeline):
//   one wave per (sample,chunk); lane (a,b)=(lane>>3,lane&7) owns S2[a][b],
//   S3[a][b][0..7]. Direct form: S3[k] += cf*dx2[k][u], cf=S2+S1*db/2+da*db/6.
//   dx/2 staged in BOTH LDS layouts (per-wave private, NO barriers):
//     Bc [c][t] stride 68          -> per-lane da/db b128 reads
//     A  [t][c] split 4+4 columns  -> uniform b128 broadcast reads (+AHOFF)
//   4-step blocks; block j+1's 10 b128 operands prefetched into named A/B
//   register sets while block j computes (compiler-managed lgkmcnt; all
//   indices compile-time). No P/Q rotation movs; scalar w/z; pk_fma S3.
// Kernel 2: per-sample in-order Chen combine of the G chunk signatures.

typedef float f2 __attribute__((ext_vector_type(2)));

constexpr int B_ = 512;
constexpr int C_ = 8;
constexpr int L_ = 8192;
constexpr int NINC = L_ - 1;      // 8191 increments
constexpr int SIGDIM = 584;       // 8 + 64 + 512
constexpr int TILE = 64;          // steps per LDS tile
constexpr int BSTR = 68;          // Bc row stride (floats)
constexpr int AHOFF = 264;        // A high-half offset (floats)
constexpr int AWSZ = 520;
constexpr int BWSZ = C_ * BSTR;   // 544

// load block J's operands (4 steps) into register set SET
#define LDP(SET, J)                                              \
  do {                                                           \
    SET##p0 = *(const float4*)(as_ + ((J) * 4 + 0) * 4);         \
    SET##p1 = *(const float4*)(as_ + ((J) * 4 + 1) * 4);         \
    SET##p2 = *(const float4*)(as_ + ((J) * 4 + 2) * 4);         \
    SET##p3 = *(const float4*)(as_ + ((J) * 4 + 3) * 4);         \
    SET##q0 = *(const float4*)(as_ + AHOFF + ((J) * 4 + 0) * 4); \
    SET##q1 = *(const float4*)(as_ + AHOFF + ((J) * 4 + 1) * 4); \
    SET##q2 = *(const float4*)(as_ + AHOFF + ((J) * 4 + 2) * 4); \
    SET##q3 = *(const float4*)(as_ + AHOFF + ((J) * 4 + 3) * 4); \
    SET##av = *(const float4*)(pa + (J) * 4);                    \
    SET##bv = *(const float4*)(pb + (J) * 4);                    \
  } while (0)

// one step on halved increments; true-scale cf/S2/S1; S3 as f2 k-pairs.
#define ST1(DA, DB, PLO, PHI)                                              \
  do {                                                                     \
    const float w_ = __builtin_fmaf((DA), (2.f / 3.f), s1a);               \
    const float z_ = __builtin_fmaf((DA), (4.f / 3.f), s1a);               \
    const float cf = __builtin_fmaf((DB), w_, S2);                         \
    S2  = __builtin_fmaf((DB), z_, cf);                                    \
    s1a = __builtin_fmaf((DA), 2.f, s1a);                                  \
    const f2 cf2 = {cf, cf};                                               \
    S3p[0] = __builtin_elementwise_fma(cf2, f2{(PLO).x, (PLO).y}, S3p[0]); \
    S3p[1] = __builtin_elementwise_fma(cf2, f2{(PLO).z, (PLO).w}, S3p[1]); \
    S3p[2] = __builtin_elementwise_fma(cf2, f2{(PHI).x, (PHI).y}, S3p[2]); \
    S3p[3] = __builtin_elementwise_fma(cf2, f2{(PHI).z, (PHI).w}, S3p[3]); \
  } while (0)

#define CB(SET)                                        \
  do {                                                 \
    ST1(SET##av.x, SET##bv.x, SET##p0, SET##q0);       \
    ST1(SET##av.y, SET##bv.y, SET##p1, SET##q1);       \
    ST1(SET##av.z, SET##bv.z, SET##p2, SET##q2);       \
    ST1(SET##av.w, SET##bv.w, SET##p3, SET##q3);       \
  } while (0)

__global__ __launch_bounds__(256, 3)
void sig_chunks_kernel(const float* __restrict__ path, float* __restrict__ csig,
                       int G, int CPC) {
  __shared__ __align__(16) float As[4][AWSZ];
  __shared__ __align__(16) float Bs[4][BWSZ];
  const int wid  = __builtin_amdgcn_readfirstlane((int)(threadIdx.x >> 6));
  const int lane = (int)(threadIdx.x & 63);
  const int ia = lane >> 3;   // 'a' == staging channel
  const int ib = lane & 7;    // 'b' == staging position
  const int wglob = __builtin_amdgcn_readfirstlane((int)blockIdx.x) * 4 + wid;
  const int samp = wglob / G;
  const int g    = wglob - samp * G;
  const int ts = g * CPC;
  const int te = (ts + CPC < NINC) ? (ts + CPC) : NINC;   // exclusive end
  const float* pbase = path + (size_t)samp * (C_ * L_);
  float* as_ = As[wid];
  float* bs  = Bs[wid];

  const int si = ib;
  const float* prow = pbase + ia * L_;
  const int grp = lane & ~7;
  float* aw = as_ + (ia >> 2) * AHOFF + (ia & 3);
  const float* pa = bs + ia * BSTR;
  const float* pb = bs + ib * BSTR;

  f2 S3p[4];
#pragma unroll
  for (int k = 0; k < 4; ++k) S3p[k] = f2{0.f, 0.f};
  float S2 = 0.f, s1a = 0.f;

  const int ntiles = (CPC + TILE - 1) / TILE;   // uniform across grid

  // prologue: prefetch tile 0 + boundary
  float4 r0 = *(const float4*)(prow + ts + si * 4);
  float4 r1 = *(const float4*)(prow + ts + 32 + si * 4);
  float bnd = prow[ts + TILE];

  float4 Ap0, Ap1, Ap2, Ap3, Aq0, Aq1, Aq2, Aq3, Aav, Abv;
  float4 Bp0, Bp1, Bp2, Bp3, Bq0, Bq1, Bq2, Bq3, Bav, Bbv;

  for (int tt = 0; tt < ntiles; ++tt) {
    const int t0 = ts + tt * TILE;
    const int cnt_ = te - t0;
    const int cnt = (cnt_ < TILE) ? cnt_ : TILE;

    // ---- stage tile tt from regs: halved diffs into both LDS layouts ----
    {
      const float4 v0 = r0, v1 = r1;
      const float sA = __shfl(v0.x, lane + 1);
      const float sB = __shfl(v1.x, grp);
      const float sC = __shfl(v1.x, lane + 1);
      const float n0 = (si == 7) ? sB : sA;
      const float n1 = (si == 7) ? bnd : sC;
      float4 d0, d1;
      d0.x = (v0.y - v0.x) * 0.5f;
      d0.y = (v0.z - v0.y) * 0.5f;
      d0.z = (v0.w - v0.z) * 0.5f;
      d0.w = (n0 - v0.w) * 0.5f;
      d1.x = (v1.y - v1.x) * 0.5f;
      d1.y = (v1.z - v1.y) * 0.5f;
      d1.z = (v1.w - v1.z) * 0.5f;
      d1.w = (n1 - v1.w) * 0.5f;
      *(float4*)(bs + ia * BSTR + si * 4) = d0;
      *(float4*)(bs + ia * BSTR + 32 + si * 4) = d1;
      const int tl = si * 4;
      aw[(tl + 0) * 4] = d0.x;
      aw[(tl + 1) * 4] = d0.y;
      aw[(tl + 2) * 4] = d0.z;
      aw[(tl + 3) * 4] = d0.w;
      aw[(32 + tl + 0) * 4] = d1.x;
      aw[(32 + tl + 1) * 4] = d1.y;
      aw[(32 + tl + 2) * 4] = d1.z;
      aw[(32 + tl + 3) * 4] = d1.w;
    }

    // ---- prefetch tile tt+1 ----
    if (tt + 1 < ntiles) {
      const int t1g = t0 + TILE;
      r0 = *(const float4*)(prow + t1g + si * 4);
      r1 = *(const float4*)(prow + t1g + 32 + si * 4);
      const int bn = t1g + TILE;
      bnd = (bn < L_) ? prow[bn] : 0.f;
    }

    // ---- compute tile tt: 16 4-step blocks, A/B register double-buffer ----
    if (cnt == TILE) {
      LDP(A, 0);
#pragma unroll
      for (int jj = 0; jj < 8; ++jj) {
        LDP(B, jj * 2 + 1);
        CB(A);
        if (jj < 7) { LDP(A, jj * 2 + 2); }
        CB(B);
      }
    } else {
      // tail tile (only the last chunk's last tile, cnt=63): cold path
      for (int blk = 0; blk < 8; ++blk) {
        const int u0 = blk * 8;
        int m = cnt - u0; if (m > 8) m = 8;
        if (m <= 0) break;
        const float4 a0 = *(const float4*)(pa + u0);
        const float4 a1 = *(const float4*)(pa + u0 + 4);
        const float4 b0 = *(const float4*)(pb + u0);
        const float4 b1 = *(const float4*)(pb + u0 + 4);
        const float da[8] = {a0.x, a0.y, a0.z, a0.w, a1.x, a1.y, a1.z, a1.w};
        const float db[8] = {b0.x, b0.y, b0.z, b0.w, b1.x, b1.y, b1.z, b1.w};
#pragma unroll
        for (int u = 0; u < 8; ++u) {
          if (u < m) {
            const float4 PLO = *(const float4*)(as_ + (u0 + u) * 4);
            const float4 PHI = *(const float4*)(as_ + AHOFF + (u0 + u) * 4);
            ST1(da[u], db[u], PLO, PHI);
          }
        }
      }
    }
  }

  float* cs = csig + ((size_t)samp * G + g) * SIGDIM;
  if (ib == 0) cs[ia] = s1a;
  cs[8 + lane] = S2;
  float4 o0, o1;
  o0.x = 2.f * S3p[0].x; o0.y = 2.f * S3p[0].y;
  o0.z = 2.f * S3p[1].x; o0.w = 2.f * S3p[1].y;
  o1.x = 2.f * S3p[2].x; o1.y = 2.f * S3p[2].y;
  o1.z = 2.f * S3p[3].x; o1.w = 2.f * S3p[3].y;
  *(float4*)(cs + 72 + lane * 8)     = o0;
  *(float4*)(cs + 72 + lane * 8 + 4) = o1;
}

__global__ __launch_bounds__(256)
void sig_combine_kernel(const float* __restrict__ csig, float* __restrict__ out, int G) {
  const int wid  = __builtin_amdgcn_readfirstlane((int)(threadIdx.x >> 6));
  const int lane = (int)(threadIdx.x & 63);
  const int ia = lane >> 3, ib = lane & 7;
  const int samp = __builtin_amdgcn_readfirstlane((int)blockIdx.x) * 4 + wid;
  const float* base = csig + (size_t)samp * G * SIGDIM;

  float R1a = base[ia];
  float R2  = base[8 + lane];
  float R3[8];
#pragma unroll
  for (int k = 0; k < 8; ++k) R3[k] = base[72 + lane * 8 + k];

  for (int g = 1; g < G; ++g) {
    const float* T = base + g * SIGDIM;
    float sT1[8];
#pragma unroll
    for (int k = 0; k < 8; ++k) sT1[k] = T[k];
    const float T1a  = T[ia];
    const float T1b  = T[ib];
    const float T2ab = T[8 + lane];
    float T2b[8], T3v[8];
#pragma unroll
    for (int k = 0; k < 8; ++k) T2b[k] = T[8 + ib * 8 + k];
#pragma unroll
    for (int k = 0; k < 8; ++k) T3v[k] = T[72 + lane * 8 + k];
    const float R1o = R1a, R2o = R2;
#pragma unroll
    for (int k = 0; k < 8; ++k)
      R3[k] += T3v[k] + R1o * T2b[k] + R2o * sT1[k];
    R2  += T2ab + R1o * T1b;
    R1a += T1a;
  }

  float* o = out + (size_t)samp * SIGDIM;
  if (ib == 0) o[ia] = R1a;
  o[8 + lane] = R2;
#pragma unroll
  for (int k = 0; k < 8; ++k) o[72 + lane * 8 + k] = R3[k];
}

extern "C" void kernel_launch(void* const* d_in, const int* in_sizes, int n_in,
                              void* d_out, int out_size, void* d_ws, size_t ws_size,
                              hipStream_t stream) {
  (void)in_sizes; (void)n_in; (void)out_size;
  const float* path = (const float*)d_in[0];
  float* out = (float*)d_out;
  float* ws  = (float*)d_ws;

  int G = 16;
  while (G > 1 && (size_t)B_ * G * SIGDIM * sizeof(float) > ws_size) G >>= 1;
  const int CPC = (NINC + G - 1) / G;   // increments per chunk

  sig_chunks_kernel<<<dim3(B_ * G / 4), dim3(256), 0, stream>>>(path, ws, G, CPC);
  sig_combine_kernel<<<dim3(B_ / 4), dim3(256), 0, stream>>>(ws, out, G);
}